// Round 3
// baseline (520.000 us; speedup 1.0000x reference)
//
#include <hip/hip_runtime.h>
#include <math.h>
#include <limits.h>

// Problem constants (from reference): N=2e6, C=64, B=16, H=32.
#define NCH   64
#define NBAT  16
#define NHID  32
#define NGRP  4     // segment groups; 4 segments/group ~ 128 MB of x, fits L3
#define SPG   4     // segments per group

typedef float f4 __attribute__((ext_vector_type(4)));

// Workspace layout (floats):
//   [0    .. 1023]  per-(b,c) sums
//   [1024 .. 2047]  per-(b,c) maxes
//   [2048 .. 2063]  per-b counts
//   [2064 .. 3087]  per-(b,c) scale = 1 + sigmoid(mlp(avg)+mlp(max))
//   [3088 .. 3103]  (as int) seg_start[b], INT_MAX if segment empty

__device__ __forceinline__ void atomicMaxF(float* addr, float v) {
    if (v >= 0.0f) atomicMax((int*)addr, __float_as_int(v));
    else           atomicMin((unsigned int*)addr, __float_as_uint(v));
}

// Group g covers rows [minseg(4g), minseg(4g+4)) where minseg(k) is the first
// row of the first non-empty segment >= k (or n).
__device__ __forceinline__ int minseg(const int* ss, int k, int n) {
    int m = n;
    for (int b = k; b < NBAT; ++b) m = min(m, ss[b]);
    return m;
}

__global__ __launch_bounds__(256) void init_kernel(float* ws) {
    int i = blockIdx.x * blockDim.x + threadIdx.x;
    if (i < 1024) {
        ws[i] = 0.0f;                  // sums
        ws[1024 + i] = -INFINITY;      // maxes
    }
    if (i < NBAT) ws[2048 + i] = 0.0f; // counts
    if (i < NBAT) ((int*)(ws + 3088))[i] = INT_MAX;
}

// Find segment start indices from the sorted batch_ids (8 MB scan).
__global__ __launch_bounds__(256) void scan_kernel(const int* __restrict__ bid,
                                                   float* __restrict__ ws, int n) {
    int* ss = (int*)(ws + 3088);
    const int stride = gridDim.x * blockDim.x;
    for (int i = blockIdx.x * blockDim.x + threadIdx.x; i < n; i += stride) {
        const int b = bid[i];
        if (i == 0) atomicMin(&ss[b], 0);
        else if (bid[i - 1] != b) atomicMin(&ss[b], i);
    }
}

__device__ __forceinline__ void flush_seg(float* __restrict__ wsum,
                                          float* __restrict__ wmax,
                                          float* __restrict__ wcnt,
                                          int b, int c4,
                                          const float4& s, const float4& m, float cnt) {
    float* ps = wsum + b * NCH + c4 * 4;
    atomicAdd(ps + 0, s.x);
    atomicAdd(ps + 1, s.y);
    atomicAdd(ps + 2, s.z);
    atomicAdd(ps + 3, s.w);
    float* pm = wmax + b * NCH + c4 * 4;
    atomicMaxF(pm + 0, m.x);
    atomicMaxF(pm + 1, m.y);
    atomicMaxF(pm + 2, m.z);
    atomicMaxF(pm + 3, m.w);
    if (c4 == 0) atomicAdd(wcnt + b, cnt);
}

// Segment-sum/max for group g's row range. Thread layout: c4 = tid&15 (channel
// group of 4 via float4), rg = tid>>4 (16 rows in flight). A wave reads 1 KiB
// contiguous. Contiguous chunk per block -> <=1 segment transition per block.
__global__ __launch_bounds__(256) void reduce_kernel(const float* __restrict__ x,
                                                     const int* __restrict__ bid,
                                                     float* __restrict__ ws,
                                                     int n, int g) {
    const int* ss = (const int*)(ws + 3088);
    const int begin = min(minseg(ss, g * SPG, n), n);
    const int end   = min(minseg(ss, g * SPG + SPG, n), n);
    const int rows = end - begin;
    if (rows <= 0) return;

    float* wsum = ws;
    float* wmax = ws + 1024;
    float* wcnt = ws + 2048;

    const int tid = threadIdx.x;
    const int c4 = tid & 15;
    const int rg = tid >> 4;
    const int rpb = (rows + gridDim.x - 1) / gridDim.x;
    const int r0 = begin + blockIdx.x * rpb;
    const int rend = min(r0 + rpb, end);

    int cur = -1;
    float4 s = make_float4(0.f, 0.f, 0.f, 0.f);
    float4 m = make_float4(-INFINITY, -INFINITY, -INFINITY, -INFINITY);
    float cnt = 0.0f;

    for (int r = r0 + rg; r < rend; r += 16) {
        int b = bid[r];
        if (b != cur) {
            if (cur >= 0) flush_seg(wsum, wmax, wcnt, cur, c4, s, m, cnt);
            cur = b;
            s = make_float4(0.f, 0.f, 0.f, 0.f);
            m = make_float4(-INFINITY, -INFINITY, -INFINITY, -INFINITY);
            cnt = 0.0f;
        }
        const float4 v = *reinterpret_cast<const float4*>(x + (size_t)r * NCH + c4 * 4);
        s.x += v.x; s.y += v.y; s.z += v.z; s.w += v.w;
        m.x = fmaxf(m.x, v.x); m.y = fmaxf(m.y, v.y);
        m.z = fmaxf(m.z, v.z); m.w = fmaxf(m.w, v.w);
        cnt += 1.0f;
    }

    // Block-level combine across the 16 row groups (same c4).
    __shared__ int    lb[256];
    __shared__ float4 ls[256];
    __shared__ float4 lm[256];
    __shared__ float  lc[256];
    lb[tid] = cur; ls[tid] = s; lm[tid] = m; lc[tid] = cnt;
    __syncthreads();
    if (rg == 0) {
        for (int gg = 1; gg < 16; ++gg) {
            int i = gg * 16 + c4;
            int ob = lb[i];
            if (ob < 0) continue;
            if (ob == cur && cur >= 0) {
                const float4 os = ls[i]; const float4 om = lm[i];
                s.x += os.x; s.y += os.y; s.z += os.z; s.w += os.w;
                m.x = fmaxf(m.x, om.x); m.y = fmaxf(m.y, om.y);
                m.z = fmaxf(m.z, om.z); m.w = fmaxf(m.w, om.w);
                cnt += lc[i];
            } else if (cur < 0) {
                cur = ob; s = ls[i]; m = lm[i]; cnt = lc[i];
            } else {
                flush_seg(wsum, wmax, wcnt, ob, c4, ls[i], lm[i], lc[i]);
            }
        }
        if (cur >= 0) flush_seg(wsum, wmax, wcnt, cur, c4, s, m, cnt);
    }
}

// Tiny MLP: recomputes all 16x64 scales from the current partial stats.
// Scales for segments already fully reduced are final; others are garbage
// that no apply launch reads yet. One block, everything in LDS.
__global__ __launch_bounds__(512) void mlp_kernel(const float* __restrict__ ws,
                                                  const float* __restrict__ W1,
                                                  const float* __restrict__ b1,
                                                  const float* __restrict__ W2,
                                                  const float* __restrict__ b2,
                                                  float* __restrict__ scale_out) {
    __shared__ float avg[NBAT * NCH];
    __shared__ float mxs[NBAT * NCH];
    __shared__ float h1a[NBAT * NHID];
    __shared__ float h1m[NBAT * NHID];
    const int t = threadIdx.x;

    for (int i = t; i < NBAT * NCH; i += 512) {
        float c = ws[2048 + (i >> 6)];
        avg[i] = ws[i] / fmaxf(c, 1.0f);
        mxs[i] = ws[1024 + i];
    }
    __syncthreads();

    {   // h1 = relu(h @ W1.T + b1), both branches. 512 threads = 16b x 32j.
        const int b = t >> 5, j = t & 31;
        float sa = b1[j], sm = b1[j];
        const float* w = W1 + j * NCH;
        for (int c = 0; c < NCH; ++c) {
            float wv = w[c];
            sa += avg[b * NCH + c] * wv;
            sm += mxs[b * NCH + c] * wv;
        }
        h1a[b * NHID + j] = fmaxf(sa, 0.0f);
        h1m[b * NHID + j] = fmaxf(sm, 0.0f);
    }
    __syncthreads();

    for (int i = t; i < NBAT * NCH; i += 512) {
        const int b = i >> 6, c = i & 63;
        float ya = b2[c], ym = b2[c];
        const float* w = W2 + c * NHID;
        for (int j = 0; j < NHID; ++j) {
            float wv = w[j];
            ya += h1a[b * NHID + j] * wv;
            ym += h1m[b * NHID + j] * wv;
        }
        float z = ya + ym;
        float sig = 1.0f / (1.0f + expf(-z));
        scale_out[i] = 1.0f + sig;  // out = x*att + x = x*(1+att)
    }
}

// out[r][c] = x[r][c] * scale[bid[r]][c] for group g's rows. Runs right after
// reduce(g), so the group's x lines are L3-resident -> reads hit L3.
// Nontemporal stores keep `out` from evicting them.
__global__ __launch_bounds__(256) void apply_kernel(const float* __restrict__ x,
                                                    const int* __restrict__ bid,
                                                    float* __restrict__ ws,
                                                    float* __restrict__ out,
                                                    int n, int g) {
    __shared__ float s_scale[NBAT * NCH];
    for (int i = threadIdx.x; i < NBAT * NCH; i += 256) s_scale[i] = ws[2064 + i];

    const int* ss = (const int*)(ws + 3088);
    const int begin = min(minseg(ss, g * SPG, n), n);
    const int end   = min(minseg(ss, g * SPG + SPG, n), n);
    const int rows = end - begin;
    __syncthreads();
    if (rows <= 0) return;

    const int c4 = threadIdx.x & 15;
    const int rg = threadIdx.x >> 4;
    const int rpb = (rows + gridDim.x - 1) / gridDim.x;
    const int r0 = begin + blockIdx.x * rpb;
    const int rend = min(r0 + rpb, end);

    for (int r = r0 + rg; r < rend; r += 16) {
        const int b = bid[r];
        const f4 v  = *reinterpret_cast<const f4*>(x + (size_t)r * NCH + c4 * 4);
        const f4 sc = *reinterpret_cast<const f4*>(s_scale + b * NCH + c4 * 4);
        const f4 o = v * sc;
        __builtin_nontemporal_store(o, reinterpret_cast<f4*>(out + (size_t)r * NCH + c4 * 4));
    }
}

extern "C" void kernel_launch(void* const* d_in, const int* in_sizes, int n_in,
                              void* d_out, int out_size, void* d_ws, size_t ws_size,
                              hipStream_t stream) {
    const float* x   = (const float*)d_in[0];
    const int*   bid = (const int*)d_in[1];
    const float* W1  = (const float*)d_in[2];
    const float* b1  = (const float*)d_in[3];
    const float* W2  = (const float*)d_in[4];
    const float* b2  = (const float*)d_in[5];
    float* out = (float*)d_out;
    const int n = in_sizes[1];  // N

    float* ws = (float*)d_ws;

    hipLaunchKernelGGL(init_kernel, dim3(4), dim3(256), 0, stream, ws);
    hipLaunchKernelGGL(scan_kernel, dim3(1024), dim3(256), 0, stream, bid, ws, n);

    for (int g = 0; g < NGRP; ++g) {
        hipLaunchKernelGGL(reduce_kernel, dim3(1024), dim3(256), 0, stream,
                           x, bid, ws, n, g);
        hipLaunchKernelGGL(mlp_kernel, dim3(1), dim3(512), 0, stream,
                           ws, W1, b1, W2, b2, ws + 2064);
        hipLaunchKernelGGL(apply_kernel, dim3(1024), dim3(256), 0, stream,
                           x, bid, ws, out, n, g);
    }
}

// Round 4
// 317.377 us; speedup vs baseline: 1.6384x; 1.6384x over previous
//
#include <hip/hip_runtime.h>
#include <math.h>

// Problem constants (from reference): N=2e6, C=64, B=16, H=32.
#define NCH   64
#define NBAT  16
#define NHID  32
#define NBLK  1024   // chunk count shared by pool and apply (1:1 mapping)

typedef float f4 __attribute__((ext_vector_type(4)));

// Workspace layout (floats):
//   [0    .. 1023]  per-(b,c) sums
//   [1024 .. 2047]  per-(b,c) maxes
//   [2048 .. 2063]  per-b counts
//   [2064 .. 3087]  per-(b,c) scale = 1 + sigmoid(mlp(avg)+mlp(max))

__device__ __forceinline__ void atomicMaxF(float* addr, float v) {
    // Monotone-lattice trick: works for mixed signs, init must be -inf.
    if (v >= 0.0f) atomicMax((int*)addr, __float_as_int(v));
    else           atomicMin((unsigned int*)addr, __float_as_uint(v));
}

__global__ __launch_bounds__(256) void init_kernel(float* ws) {
    int i = blockIdx.x * blockDim.x + threadIdx.x;
    if (i < 1024) {
        ws[i] = 0.0f;                  // sums
        ws[1024 + i] = -INFINITY;      // maxes
    }
    if (i < NBAT) ws[2048 + i] = 0.0f; // counts
}

__device__ __forceinline__ void flush_seg(float* __restrict__ wsum,
                                          float* __restrict__ wmax,
                                          float* __restrict__ wcnt,
                                          int b, int c4,
                                          const float4& s, const float4& m, float cnt) {
    float* ps = wsum + b * NCH + c4 * 4;
    atomicAdd(ps + 0, s.x);
    atomicAdd(ps + 1, s.y);
    atomicAdd(ps + 2, s.z);
    atomicAdd(ps + 3, s.w);
    float* pm = wmax + b * NCH + c4 * 4;
    atomicMaxF(pm + 0, m.x);
    atomicMaxF(pm + 1, m.y);
    atomicMaxF(pm + 2, m.z);
    atomicMaxF(pm + 3, m.w);
    if (c4 == 0) atomicAdd(wcnt + b, cnt);
}

// Each block handles a contiguous chunk of rows. Thread layout:
//   c4 = tid & 15  -> channel group (4 consecutive channels via float4)
//   rg = tid >> 4  -> row group (16 rows in flight per iteration)
// A full wave (64 lanes) reads 4 consecutive rows x 256B = 1 KiB contiguous.
__global__ __launch_bounds__(256) void pool_kernel(const float* __restrict__ x,
                                                   const int* __restrict__ bid,
                                                   float* __restrict__ wsum,
                                                   float* __restrict__ wmax,
                                                   float* __restrict__ wcnt,
                                                   int n, int rpb) {
    const int tid = threadIdx.x;
    const int c4 = tid & 15;
    const int rg = tid >> 4;
    const int r0 = blockIdx.x * rpb;
    const int rend = min(r0 + rpb, n);

    int cur = -1;
    float4 s = make_float4(0.f, 0.f, 0.f, 0.f);
    float4 m = make_float4(-INFINITY, -INFINITY, -INFINITY, -INFINITY);
    float cnt = 0.0f;

    for (int r = r0 + rg; r < rend; r += 16) {
        int b = bid[r];
        if (b != cur) {
            if (cur >= 0) flush_seg(wsum, wmax, wcnt, cur, c4, s, m, cnt);
            cur = b;
            s = make_float4(0.f, 0.f, 0.f, 0.f);
            m = make_float4(-INFINITY, -INFINITY, -INFINITY, -INFINITY);
            cnt = 0.0f;
        }
        const float4 v = *reinterpret_cast<const float4*>(x + (size_t)r * NCH + c4 * 4);
        s.x += v.x; s.y += v.y; s.z += v.z; s.w += v.w;
        m.x = fmaxf(m.x, v.x); m.y = fmaxf(m.y, v.y);
        m.z = fmaxf(m.z, v.z); m.w = fmaxf(m.w, v.w);
        cnt += 1.0f;
    }

    // Block-level combine across the 16 row groups (same c4) to cut atomic
    // contention ~16x. Sorted ids -> almost always one batch per block;
    // mismatched entries (block straddles a boundary) flush directly.
    __shared__ int    lb[256];
    __shared__ float4 ls[256];
    __shared__ float4 lm[256];
    __shared__ float  lc[256];
    lb[tid] = cur; ls[tid] = s; lm[tid] = m; lc[tid] = cnt;
    __syncthreads();
    if (rg == 0) {
        for (int g = 1; g < 16; ++g) {
            int i = g * 16 + c4;
            int ob = lb[i];
            if (ob < 0) continue;
            if (ob == cur && cur >= 0) {
                const float4 os = ls[i]; const float4 om = lm[i];
                s.x += os.x; s.y += os.y; s.z += os.z; s.w += os.w;
                m.x = fmaxf(m.x, om.x); m.y = fmaxf(m.y, om.y);
                m.z = fmaxf(m.z, om.z); m.w = fmaxf(m.w, om.w);
                cnt += lc[i];
            } else if (cur < 0) {
                cur = ob; s = ls[i]; m = lm[i]; cnt = lc[i];
            } else {
                flush_seg(wsum, wmax, wcnt, ob, c4, ls[i], lm[i], lc[i]);
            }
        }
        if (cur >= 0) flush_seg(wsum, wmax, wcnt, cur, c4, s, m, cnt);
    }
}

// Tiny MLP on pooled stats: one block, everything in LDS.
__global__ __launch_bounds__(512) void mlp_kernel(const float* __restrict__ ws,
                                                  const float* __restrict__ W1,
                                                  const float* __restrict__ b1,
                                                  const float* __restrict__ W2,
                                                  const float* __restrict__ b2,
                                                  float* __restrict__ scale_out) {
    __shared__ float avg[NBAT * NCH];
    __shared__ float mxs[NBAT * NCH];
    __shared__ float h1a[NBAT * NHID];
    __shared__ float h1m[NBAT * NHID];
    const int t = threadIdx.x;

    for (int i = t; i < NBAT * NCH; i += 512) {
        float c = ws[2048 + (i >> 6)];
        avg[i] = ws[i] / fmaxf(c, 1.0f);
        mxs[i] = ws[1024 + i];
    }
    __syncthreads();

    {   // h1 = relu(h @ W1.T + b1), for both branches. 512 threads = 16b x 32j.
        const int b = t >> 5, j = t & 31;
        float sa = b1[j], sm = b1[j];
        const float* w = W1 + j * NCH;
        for (int c = 0; c < NCH; ++c) {
            float wv = w[c];
            sa += avg[b * NCH + c] * wv;
            sm += mxs[b * NCH + c] * wv;
        }
        h1a[b * NHID + j] = fmaxf(sa, 0.0f);
        h1m[b * NHID + j] = fmaxf(sm, 0.0f);
    }
    __syncthreads();

    for (int i = t; i < NBAT * NCH; i += 512) {
        const int b = i >> 6, c = i & 63;
        float ya = b2[c], ym = b2[c];
        const float* w = W2 + c * NHID;
        for (int j = 0; j < NHID; ++j) {
            float wv = w[j];
            ya += h1a[b * NHID + j] * wv;
            ym += h1m[b * NHID + j] * wv;
        }
        float z = ya + ym;
        float sig = 1.0f / (1.0f + expf(-z));
        scale_out[i] = 1.0f + sig;  // out = x*att + x = x*(1+att)
    }
}

// out[r][c] = x[r][c] * scale[bid[r]][c].
// Block i covers EXACTLY pool block i's chunk, traversed TAIL-FIRST: pool's
// blocks streamed their chunks in parallel, so at pool-end L3 holds the tail
// of every chunk (not the address-space tail). Re-reading own-chunk tail
// first maximizes L3 hits before other blocks' misses evict those lines.
// Nontemporal stores keep `out` from evicting the x working set.
__global__ __launch_bounds__(256) void apply_kernel(const float* __restrict__ x,
                                                    const int* __restrict__ bid,
                                                    const float* __restrict__ scale,
                                                    float* __restrict__ out,
                                                    int n, int rpb) {
    __shared__ float s_scale[NBAT * NCH];
    for (int i = threadIdx.x; i < NBAT * NCH; i += 256) s_scale[i] = scale[i];
    __syncthreads();

    const int r0 = blockIdx.x * rpb;
    const int rend = min(r0 + rpb, n);
    const int c4 = threadIdx.x & 15;
    const int rg = threadIdx.x >> 4;
    const int base = r0 + rg;
    if (base >= rend) return;

    const int iters = (rend - base + 15) >> 4;
    for (int k = iters - 1; k >= 0; --k) {
        const int r = base + (k << 4);
        const int b = bid[r];
        const f4 v  = *reinterpret_cast<const f4*>(x + (size_t)r * NCH + c4 * 4);
        const f4 sc = *reinterpret_cast<const f4*>(s_scale + b * NCH + c4 * 4);
        const f4 o = v * sc;
        __builtin_nontemporal_store(o, reinterpret_cast<f4*>(out + (size_t)r * NCH + c4 * 4));
    }
}

extern "C" void kernel_launch(void* const* d_in, const int* in_sizes, int n_in,
                              void* d_out, int out_size, void* d_ws, size_t ws_size,
                              hipStream_t stream) {
    const float* x   = (const float*)d_in[0];
    const int*   bid = (const int*)d_in[1];
    const float* W1  = (const float*)d_in[2];
    const float* b1  = (const float*)d_in[3];
    const float* W2  = (const float*)d_in[4];
    const float* b2  = (const float*)d_in[5];
    float* out = (float*)d_out;
    const int n = in_sizes[1];  // N (batch_ids element count)

    float* ws     = (float*)d_ws;
    float* wsum   = ws;
    float* wmax   = ws + 1024;
    float* wcnt   = ws + 2048;
    float* wscale = ws + 2064;

    hipLaunchKernelGGL(init_kernel, dim3(4), dim3(256), 0, stream, ws);

    const int rpb = (n + NBLK - 1) / NBLK;
    hipLaunchKernelGGL(pool_kernel, dim3(NBLK), dim3(256), 0, stream,
                       x, bid, wsum, wmax, wcnt, n, rpb);

    hipLaunchKernelGGL(mlp_kernel, dim3(1), dim3(512), 0, stream,
                       ws, W1, b1, W2, b2, wscale);

    hipLaunchKernelGGL(apply_kernel, dim3(NBLK), dim3(256), 0, stream,
                       x, bid, wscale, out, n, rpb);
}